// Round 2
// baseline (584.891 us; speedup 1.0000x reference)
//
#include <hip/hip_runtime.h>
#include <hip/hip_bf16.h>

#define F_NODE 128
#define F_EDGE 128
#define OUT_W  384   // F_NODE + (F_NODE + F_EDGE)

// ---------------------------------------------------------------------------
// Kernel 1: count edges per destination node (counts pre-zeroed)
// ---------------------------------------------------------------------------
__global__ void count_kernel(const int* __restrict__ row, int* __restrict__ counts, int E) {
    int e = blockIdx.x * blockDim.x + threadIdx.x;
    if (e < E) atomicAdd(&counts[row[e]], 1);
}

// ---------------------------------------------------------------------------
// Kernel 2: exclusive scan of counts -> offsets[0..n] + cursor copy.
// 256 threads, each owns a sequential chunk; wave shfl-scan of chunk sums;
// exactly ONE __syncthreads.
// ---------------------------------------------------------------------------
__global__ __launch_bounds__(256) void scan_kernel(const int* __restrict__ counts,
                                                   int* __restrict__ offsets,
                                                   int* __restrict__ cursor, int n) {
    const int t = threadIdx.x;
    const int chunk = (n + 255) / 256;
    const int lo = t * chunk;
    const int hi = min(lo + chunk, n);

    int local = 0;
    for (int i = lo; i < hi; ++i) local += counts[i];

    // block-wide exclusive scan of 256 per-thread sums
    const int lane = t & 63, wv = t >> 6;
    int incl = local;
    for (int d = 1; d < 64; d <<= 1) {
        int v = __shfl_up(incl, d);
        if (lane >= d) incl += v;
    }
    __shared__ int wsum[4];
    if (lane == 63) wsum[wv] = incl;
    __syncthreads();
    int wpre = 0;
    for (int w = 0; w < wv; ++w) wpre += wsum[w];
    int run = wpre + incl - local;   // exclusive prefix for this chunk

    for (int i = lo; i < hi; ++i) {
        offsets[i] = run;
        cursor[i]  = run;
        run += counts[i];
    }
    if (t == 255) offsets[n] = wpre + incl;   // grand total (== E)
}

// ---------------------------------------------------------------------------
// Kernel 3: CSR bucket build. Writes packed (edge_id, col_id) pairs so the
// aggregate kernel has a single indirection.
// ---------------------------------------------------------------------------
__global__ void scatter_kernel(const int* __restrict__ row, const int* __restrict__ col,
                               int* __restrict__ cursor, int2* __restrict__ pairs, int E) {
    int e = blockIdx.x * blockDim.x + threadIdx.x;
    if (e < E) {
        int r = row[e];
        int c = col[e];
        int pos = atomicAdd(&cursor[r], 1);
        pairs[pos] = make_int2(e, c);
    }
}

// ---------------------------------------------------------------------------
// Kernel 4: per-node aggregation. ONE WAVE per node (4 waves/block), zero
// barriers. Lane i preloads pair i of a 64-edge tile; inner loop broadcasts
// (e,c) via __shfl; each lane float4-loads 16B: lanes 0-31 cover x[c][:],
// lanes 32-63 cover edge_attr[e][:], selected branchlessly.
// ---------------------------------------------------------------------------
__global__ __launch_bounds__(256) void aggregate_kernel(
    const float* __restrict__ x, const float* __restrict__ edge_attr,
    const int* __restrict__ offsets, const int2* __restrict__ pairs,
    float* __restrict__ out, int n_nodes) {

    const int wave = threadIdx.x >> 6;
    const int lane = threadIdx.x & 63;
    const int node = blockIdx.x * 4 + wave;
    if (node >= n_nodes) return;

    const int start = offsets[node];
    const int end   = offsets[node + 1];
    const int cnt   = end - start;

    const bool is_x = lane < 32;
    const int  sub4 = (is_x ? lane : (lane - 32)) * 4;   // float offset in row

    float4 sum = make_float4(0.f, 0.f, 0.f, 0.f);

    for (int base = start; base < end; base += 64) {
        const int m = min(64, end - base);
        int idx = base + lane;
        if (idx >= end) idx = end - 1;          // clamp; lanes >= m unused
        const int2 pr = pairs[idx];             // (e, c)
        for (int i = 0; i < m; ++i) {
            const int e = __shfl(pr.x, i);
            const int c = __shfl(pr.y, i);
            const float* px = x         + (size_t)c * F_NODE;
            const float* pe = edge_attr + (size_t)e * F_EDGE;
            const float* p  = (is_x ? px : pe) + sub4;
            const float4 v = *(const float4*)p;
            sum.x += v.x; sum.y += v.y; sum.z += v.z; sum.w += v.w;
        }
    }

    const float inv = 1.0f / fmaxf((float)cnt, 1.0f);
    float* orow = out + (size_t)node * OUT_W;

    float4 mean = make_float4(sum.x * inv, sum.y * inv, sum.z * inv, sum.w * inv);
    *(float4*)(orow + F_NODE + lane * 4) = mean;            // cols 128..383

    const float* xr = x + (size_t)node * F_NODE;            // cols 0..127
    *(float2*)(orow + lane * 2) = *(const float2*)(xr + lane * 2);
}

// ---------------------------------------------------------------------------
extern "C" void kernel_launch(void* const* d_in, const int* in_sizes, int n_in,
                              void* d_out, int out_size, void* d_ws, size_t ws_size,
                              hipStream_t stream) {
    const float* x          = (const float*)d_in[0];
    const int*   edge_index = (const int*)d_in[1];
    const float* edge_attr  = (const float*)d_in[2];

    const int n_nodes = in_sizes[0] / F_NODE;      // 10000
    const int E       = in_sizes[1] / 2;           // 640000
    const int* row = edge_index;                   // destinations
    const int* col = edge_index + E;               // sources

    // workspace layout: pairs first (8B aligned), then int arrays
    int2* pairs   = (int2*)d_ws;                   // E int2
    int*  counts  = (int*)(pairs + E);             // n_nodes
    int*  offsets = counts + n_nodes;              // n_nodes + 1
    int*  cursor  = offsets + n_nodes + 1;         // n_nodes

    float* out = (float*)d_out;

    hipMemsetAsync(counts, 0, (size_t)n_nodes * sizeof(int), stream);

    const int TB = 256;
    count_kernel<<<(E + TB - 1) / TB, TB, 0, stream>>>(row, counts, E);
    scan_kernel<<<1, 256, 0, stream>>>(counts, offsets, cursor, n_nodes);
    scatter_kernel<<<(E + TB - 1) / TB, TB, 0, stream>>>(row, col, cursor, pairs, E);
    aggregate_kernel<<<(n_nodes + 3) / 4, 256, 0, stream>>>(x, edge_attr, offsets,
                                                            pairs, out, n_nodes);
}

// Round 3
// 512.281 us; speedup vs baseline: 1.1417x; 1.1417x over previous
//
#include <hip/hip_runtime.h>

#define F      128
#define OUT_W  384
#define NBLK   128   // counting-sort blocks
#define HT     512   // threads per hist/scatter block

typedef __attribute__((ext_vector_type(4))) float f4;

// ---------------------------------------------------------------------------
// K1: per-block LDS-privatized histogram of destinations. No global atomics.
// ---------------------------------------------------------------------------
__global__ __launch_bounds__(HT) void hist_kernel(const int* __restrict__ row,
                                                  int* __restrict__ hist,
                                                  int E, int N, int chunk) {
    extern __shared__ int h[];
    const int t = threadIdx.x;
    for (int i = t; i < N; i += HT) h[i] = 0;
    __syncthreads();
    const int lo = blockIdx.x * chunk;
    const int hi = min(lo + chunk, E);
    for (int i = lo + t; i < hi; i += HT) atomicAdd(&h[row[i]], 1);
    __syncthreads();
    int* dst = hist + (size_t)blockIdx.x * N;
    for (int i = t; i < N; i += HT) dst[i] = h[i];
}

// ---------------------------------------------------------------------------
// K2: per-node total over the NBLK block-histograms (coalesced across lanes)
// ---------------------------------------------------------------------------
__global__ void totals_kernel(const int* __restrict__ hist, int* __restrict__ tot, int N) {
    const int n = blockIdx.x * blockDim.x + threadIdx.x;
    if (n >= N) return;
    int s = 0;
    for (int b = 0; b < NBLK; ++b) s += hist[(size_t)b * N + n];
    tot[n] = s;
}

// ---------------------------------------------------------------------------
// K3: single-block exclusive scan of totals -> offsets[0..N]; ONE barrier
// ---------------------------------------------------------------------------
__global__ __launch_bounds__(1024) void scan_kernel(const int* __restrict__ tot,
                                                    int* __restrict__ offsets, int N) {
    const int t = threadIdx.x;
    const int chunk = (N + 1023) / 1024;
    const int lo = min(t * chunk, N);
    const int hi = min(lo + chunk, N);
    int local = 0;
    for (int i = lo; i < hi; ++i) local += tot[i];
    const int lane = t & 63, wv = t >> 6;
    int incl = local;
    for (int d = 1; d < 64; d <<= 1) {
        int v = __shfl_up(incl, d);
        if (lane >= d) incl += v;
    }
    __shared__ int wsum[16];
    if (lane == 63) wsum[wv] = incl;
    __syncthreads();
    int wpre = 0;
    for (int w = 0; w < wv; ++w) wpre += wsum[w];
    int run = wpre + incl - local;
    for (int i = lo; i < hi; ++i) { offsets[i] = run; run += tot[i]; }
    if (t == 1023) offsets[N] = wpre + incl;   // == E
}

// ---------------------------------------------------------------------------
// K4: per-node running prefix across blocks; hist becomes per-block start
// ---------------------------------------------------------------------------
__global__ void blockstart_kernel(int* hist, const int* __restrict__ offsets, int N) {
    const int n = blockIdx.x * blockDim.x + threadIdx.x;
    if (n >= N) return;
    int run = offsets[n];
    for (int b = 0; b < NBLK; ++b) {
        const size_t k = (size_t)b * N + n;
        const int v = hist[k];
        hist[k] = run;
        run += v;
    }
}

// ---------------------------------------------------------------------------
// K5: place edges. LDS cursors only (no global atomics). SoA eid/cid output.
// ---------------------------------------------------------------------------
__global__ __launch_bounds__(HT) void scatter_kernel(const int* __restrict__ row,
                                                     const int* __restrict__ col,
                                                     const int* __restrict__ hist,
                                                     int* __restrict__ eid,
                                                     int* __restrict__ cid,
                                                     int E, int N, int chunk) {
    extern __shared__ int cur[];
    const int t = threadIdx.x;
    const int* src = hist + (size_t)blockIdx.x * N;
    for (int i = t; i < N; i += HT) cur[i] = src[i];
    __syncthreads();
    const int lo = blockIdx.x * chunk;
    const int hi = min(lo + chunk, E);
    for (int i = lo + t; i < hi; i += HT) {
        const int r = row[i];
        const int p = atomicAdd(&cur[r], 1);
        eid[p] = i;
        cid[p] = col[i];
    }
}

// ---------------------------------------------------------------------------
// K6: aggregation. 2 waves per node: half 0 sums x[cid[*]], half 1 streams
// edge_attr[eid[*]] with nontemporal loads. 2 edges/iter, no barriers.
// ---------------------------------------------------------------------------
template <bool NT>
__device__ __forceinline__ void accum_half(const float* __restrict__ mat,
                                           const int* __restrict__ list,
                                           int start, int end, int lane, f4& acc) {
    const int which = lane >> 5;
    const int sub   = lane & 31;
    for (int base = start; base < end; base += 64) {
        const int m = min(64, end - base);
        int idx = base + lane;
        if (idx >= end) idx = end - 1;
        const int myid = list[idx];
        const int full = m & ~1;
        for (int i = 0; i < full; i += 2) {
            const int id = __shfl(myid, i + which);
            const f4* p = (const f4*)(mat + (size_t)id * F + sub * 4);
            const f4 v = NT ? __builtin_nontemporal_load(p) : *p;
            acc += v;
        }
        if (m & 1) {
            const int id = __shfl(myid, full);
            if (which == 0) {
                const f4* p = (const f4*)(mat + (size_t)id * F + sub * 4);
                const f4 v = NT ? __builtin_nontemporal_load(p) : *p;
                acc += v;
            }
        }
    }
}

__global__ __launch_bounds__(256) void aggregate_kernel(
    const float* __restrict__ x, const float* __restrict__ edge_attr,
    const int* __restrict__ offsets, const int* __restrict__ eid,
    const int* __restrict__ cid, float* __restrict__ out, int N) {

    const int wave = threadIdx.x >> 6;
    const int lane = threadIdx.x & 63;
    const int wid  = blockIdx.x * 4 + wave;
    const int node = wid >> 1;
    const int half = wid & 1;
    if (node >= N) return;

    const int start = offsets[node];
    const int end   = offsets[node + 1];

    f4 acc = {0.f, 0.f, 0.f, 0.f};
    if (half == 0) accum_half<false>(x,         cid, start, end, lane, acc);
    else           accum_half<true >(edge_attr, eid, start, end, lane, acc);

    // fold odd-edge lanes (32..63) into even-edge lanes (0..31)
    acc.x += __shfl_xor(acc.x, 32);
    acc.y += __shfl_xor(acc.y, 32);
    acc.z += __shfl_xor(acc.z, 32);
    acc.w += __shfl_xor(acc.w, 32);

    const float inv = 1.0f / fmaxf((float)(end - start), 1.0f);
    const int which = lane >> 5, sub = lane & 31;
    float* orow = out + (size_t)node * OUT_W;

    if (half == 0) {
        if (which == 0) {
            f4 mean = {acc.x * inv, acc.y * inv, acc.z * inv, acc.w * inv};
            *(f4*)(orow + F + sub * 4) = mean;               // cols 128..255
        } else {
            *(f4*)(orow + sub * 4) =                          // cols 0..127
                *(const f4*)(x + (size_t)node * F + sub * 4);
        }
    } else if (which == 0) {
        f4 mean = {acc.x * inv, acc.y * inv, acc.z * inv, acc.w * inv};
        *(f4*)(orow + 2 * F + sub * 4) = mean;               // cols 256..383
    }
}

// ---------------------------------------------------------------------------
extern "C" void kernel_launch(void* const* d_in, const int* in_sizes, int n_in,
                              void* d_out, int out_size, void* d_ws, size_t ws_size,
                              hipStream_t stream) {
    const float* x          = (const float*)d_in[0];
    const int*   edge_index = (const int*)d_in[1];
    const float* edge_attr  = (const float*)d_in[2];

    const int N = in_sizes[0] / F;        // 10000 nodes
    const int E = in_sizes[1] / 2;        // 640000 edges
    const int* row = edge_index;          // destinations
    const int* col = edge_index + E;      // sources

    // workspace layout (ints)
    int* hist    = (int*)d_ws;            // NBLK * N
    int* tot     = hist + (size_t)NBLK * N;  // N
    int* offsets = tot + N;               // N + 1
    int* eid     = offsets + N + 1;       // E
    int* cid     = eid + E;               // E

    float* out = (float*)d_out;

    const int chunk  = (E + NBLK - 1) / NBLK;
    const size_t smem = (size_t)N * sizeof(int);

    hist_kernel      <<<NBLK, HT, smem, stream>>>(row, hist, E, N, chunk);
    totals_kernel    <<<(N + 255) / 256, 256, 0, stream>>>(hist, tot, N);
    scan_kernel      <<<1, 1024, 0, stream>>>(tot, offsets, N);
    blockstart_kernel<<<(N + 255) / 256, 256, 0, stream>>>(hist, offsets, N);
    scatter_kernel   <<<NBLK, HT, smem, stream>>>(row, col, hist, eid, cid, E, N, chunk);
    aggregate_kernel <<<(2 * N + 3) / 4, 256, 0, stream>>>(x, edge_attr, offsets,
                                                           eid, cid, out, N);
}

// Round 4
// 486.762 us; speedup vs baseline: 1.2016x; 1.0524x over previous
//
#include <hip/hip_runtime.h>

#define F      128
#define OUT_W  384
#define NBLK   64    // counting-sort blocks
#define HT     512   // threads per hist/scatter block

typedef __attribute__((ext_vector_type(4))) float f4;

// ---------------------------------------------------------------------------
// K1: per-block LDS-privatized histogram of destinations. No global atomics.
// ---------------------------------------------------------------------------
__global__ __launch_bounds__(HT) void hist_kernel(const int* __restrict__ row,
                                                  int* __restrict__ hist,
                                                  int E, int N, int chunk) {
    extern __shared__ int h[];
    const int t = threadIdx.x;
    for (int i = t; i < N; i += HT) h[i] = 0;
    __syncthreads();
    const int lo = blockIdx.x * chunk;
    const int hi = min(lo + chunk, E);
    for (int i = lo + t; i < hi; i += HT) atomicAdd(&h[row[i]], 1);
    __syncthreads();
    int* dst = hist + (size_t)blockIdx.x * N;
    for (int i = t; i < N; i += HT) dst[i] = h[i];
}

// ---------------------------------------------------------------------------
// K2: per-node total over the NBLK block-histograms (coalesced across lanes)
// ---------------------------------------------------------------------------
__global__ void totals_kernel(const int* __restrict__ hist, int* __restrict__ tot, int N) {
    const int n = blockIdx.x * blockDim.x + threadIdx.x;
    if (n >= N) return;
    int s = 0;
    for (int b = 0; b < NBLK; ++b) s += hist[(size_t)b * N + n];
    tot[n] = s;
}

// ---------------------------------------------------------------------------
// K3: single-block exclusive scan of totals -> offsets[0..N]; ONE barrier
// ---------------------------------------------------------------------------
__global__ __launch_bounds__(1024) void scan_kernel(const int* __restrict__ tot,
                                                    int* __restrict__ offsets, int N) {
    const int t = threadIdx.x;
    const int chunk = (N + 1023) / 1024;
    const int lo = min(t * chunk, N);
    const int hi = min(lo + chunk, N);
    int local = 0;
    for (int i = lo; i < hi; ++i) local += tot[i];
    const int lane = t & 63, wv = t >> 6;
    int incl = local;
    for (int d = 1; d < 64; d <<= 1) {
        int v = __shfl_up(incl, d);
        if (lane >= d) incl += v;
    }
    __shared__ int wsum[16];
    if (lane == 63) wsum[wv] = incl;
    __syncthreads();
    int wpre = 0;
    for (int w = 0; w < wv; ++w) wpre += wsum[w];
    int run = wpre + incl - local;
    for (int i = lo; i < hi; ++i) { offsets[i] = run; run += tot[i]; }
    if (t == 1023) offsets[N] = wpre + incl;   // == E
}

// ---------------------------------------------------------------------------
// K4: per-node running prefix across blocks; hist becomes per-block start
// ---------------------------------------------------------------------------
__global__ void blockstart_kernel(int* hist, const int* __restrict__ offsets, int N) {
    const int n = blockIdx.x * blockDim.x + threadIdx.x;
    if (n >= N) return;
    int run = offsets[n];
    for (int b = 0; b < NBLK; ++b) {
        const size_t k = (size_t)b * N + n;
        const int v = hist[k];
        hist[k] = run;
        run += v;
    }
}

// ---------------------------------------------------------------------------
// K5: place edge ids. LDS cursors only; single scattered dword store per edge.
// ---------------------------------------------------------------------------
__global__ __launch_bounds__(HT) void scatter_kernel(const int* __restrict__ row,
                                                     const int* __restrict__ hist,
                                                     int* __restrict__ eid,
                                                     int E, int N, int chunk) {
    extern __shared__ int cur[];
    const int t = threadIdx.x;
    const int* src = hist + (size_t)blockIdx.x * N;
    for (int i = t; i < N; i += HT) cur[i] = src[i];
    __syncthreads();
    const int lo = blockIdx.x * chunk;
    const int hi = min(lo + chunk, E);
    for (int i = lo + t; i < hi; i += HT) {
        const int p = atomicAdd(&cur[row[i]], 1);
        eid[p] = i;
    }
}

// ---------------------------------------------------------------------------
// K6: aggregation. 2 waves per node: half 0 sums x[col[eid[*]]] (L2/L3-
// resident), half 1 streams edge_attr[eid[*]] nontemporally. 8-edge unrolled
// inner loop -> 4 independent 16 B loads in flight per lane. No barriers.
// ---------------------------------------------------------------------------
template <bool NT>
__device__ __forceinline__ f4 row_ld(const float* __restrict__ mat, int id, int sub) {
    const f4* p = (const f4*)(mat + (size_t)id * F + sub * 4);
    return NT ? __builtin_nontemporal_load(p) : *p;
}

template <bool NT>
__device__ __forceinline__ void accum_half(const float* __restrict__ mat,
                                           const int* __restrict__ eid,
                                           const int* __restrict__ colmap,
                                           int start, int end, int lane, f4& acc) {
    const int which = lane >> 5;
    const int sub   = lane & 31;
    for (int base = start; base < end; base += 64) {
        const int m = min(64, end - base);
        int idx = base + lane;
        if (idx >= end) idx = end - 1;          // clamp; lanes >= m never selected
        int myid = eid[idx];
        if (colmap) myid = colmap[myid];        // wave-uniform branch
        int i = 0;
        for (; i + 8 <= m; i += 8) {
            const int id0 = __shfl(myid, i + 0 + which);
            const int id1 = __shfl(myid, i + 2 + which);
            const int id2 = __shfl(myid, i + 4 + which);
            const int id3 = __shfl(myid, i + 6 + which);
            const f4 v0 = row_ld<NT>(mat, id0, sub);
            const f4 v1 = row_ld<NT>(mat, id1, sub);
            const f4 v2 = row_ld<NT>(mat, id2, sub);
            const f4 v3 = row_ld<NT>(mat, id3, sub);
            acc += v0; acc += v1; acc += v2; acc += v3;
        }
        const int full = m & ~1;
        for (; i < full; i += 2) {
            const int id = __shfl(myid, i + which);
            acc += row_ld<NT>(mat, id, sub);
        }
        if (m & 1) {
            const int id = __shfl(myid, full);
            if (which == 0) acc += row_ld<NT>(mat, id, sub);
        }
    }
}

__global__ __launch_bounds__(256) void aggregate_kernel(
    const float* __restrict__ x, const float* __restrict__ edge_attr,
    const int* __restrict__ col, const int* __restrict__ offsets,
    const int* __restrict__ eid, float* __restrict__ out, int N) {

    const int wave = threadIdx.x >> 6;
    const int lane = threadIdx.x & 63;
    const int wid  = blockIdx.x * 4 + wave;
    const int node = wid >> 1;
    const int half = wid & 1;
    if (node >= N) return;

    const int start = offsets[node];
    const int end   = offsets[node + 1];

    f4 acc = {0.f, 0.f, 0.f, 0.f};
    if (half == 0) accum_half<false>(x,         eid, col,     start, end, lane, acc);
    else           accum_half<true >(edge_attr, eid, nullptr, start, end, lane, acc);

    // fold odd-edge lanes (32..63) into even-edge lanes (0..31)
    acc.x += __shfl_xor(acc.x, 32);
    acc.y += __shfl_xor(acc.y, 32);
    acc.z += __shfl_xor(acc.z, 32);
    acc.w += __shfl_xor(acc.w, 32);

    const float inv = 1.0f / fmaxf((float)(end - start), 1.0f);
    const int which = lane >> 5, sub = lane & 31;
    float* orow = out + (size_t)node * OUT_W;

    if (half == 0) {
        if (which == 0) {
            f4 mean = {acc.x * inv, acc.y * inv, acc.z * inv, acc.w * inv};
            *(f4*)(orow + F + sub * 4) = mean;               // cols 128..255
        } else {
            *(f4*)(orow + sub * 4) =                          // cols 0..127
                *(const f4*)(x + (size_t)node * F + sub * 4);
        }
    } else if (which == 0) {
        f4 mean = {acc.x * inv, acc.y * inv, acc.z * inv, acc.w * inv};
        *(f4*)(orow + 2 * F + sub * 4) = mean;               // cols 256..383
    }
}

// ---------------------------------------------------------------------------
extern "C" void kernel_launch(void* const* d_in, const int* in_sizes, int n_in,
                              void* d_out, int out_size, void* d_ws, size_t ws_size,
                              hipStream_t stream) {
    const float* x          = (const float*)d_in[0];
    const int*   edge_index = (const int*)d_in[1];
    const float* edge_attr  = (const float*)d_in[2];

    const int N = in_sizes[0] / F;        // 10000 nodes
    const int E = in_sizes[1] / 2;        // 640000 edges
    const int* row = edge_index;          // destinations
    const int* col = edge_index + E;      // sources

    // workspace layout (ints)
    int* hist    = (int*)d_ws;               // NBLK * N
    int* tot     = hist + (size_t)NBLK * N;  // N
    int* offsets = tot + N;                  // N + 1
    int* eid     = offsets + N + 1;          // E

    float* out = (float*)d_out;

    const int chunk  = (E + NBLK - 1) / NBLK;
    const size_t smem = (size_t)N * sizeof(int);

    hist_kernel      <<<NBLK, HT, smem, stream>>>(row, hist, E, N, chunk);
    totals_kernel    <<<(N + 255) / 256, 256, 0, stream>>>(hist, tot, N);
    scan_kernel      <<<1, 1024, 0, stream>>>(tot, offsets, N);
    blockstart_kernel<<<(N + 255) / 256, 256, 0, stream>>>(hist, offsets, N);
    scatter_kernel   <<<NBLK, HT, smem, stream>>>(row, hist, eid, E, N, chunk);
    aggregate_kernel <<<(2 * N + 3) / 4, 256, 0, stream>>>(x, edge_attr, col,
                                                           offsets, eid, out, N);
}